// Round 1
// baseline (354.908 us; speedup 1.0000x reference)
//
#include <hip/hip_runtime.h>

// Problem constants
#define CK      27      // C*KH*KW = 3*3*3
#define CKP     28      // padded: [0..26]=s, [27] = 0.5*|s|^2  (patch side gets -1)
#define NCELL   256     // 16x16 SOM cells
#define NOUT    15      // (32-3)/2+1
#define NPATCH  225     // 15*15
#define BATCH   2048
#define FEATDIM 450     // 2*225

// ---------------------------------------------------------------------------
// Kernel 1: augment SOM rows: saug[c][k] = som[c][k] (k<27), saug[c][27] = 0.5*|s_c|^2
// ---------------------------------------------------------------------------
__global__ void prep_som(const float* __restrict__ som, float* __restrict__ saug) {
    int c = threadIdx.x;           // one block of 256 threads, one cell each
    float s2 = 0.f;
    #pragma unroll
    for (int k = 0; k < CK; ++k) {
        float v = som[c * CK + k];
        saug[c * CKP + k] = v;
        s2 = fmaf(v, v, s2);
    }
    saug[c * CKP + CK] = 0.5f * s2;
}

// ---------------------------------------------------------------------------
// Kernel 2: SOM forward. One block per image, one thread per patch.
// score_c = p.s_c - 0.5|s_c|^2 ; argmin dist == argmax score (strict > keeps
// the first max, matching torch/jnp argmin first-occurrence tie-break).
// ---------------------------------------------------------------------------
__global__ __launch_bounds__(256) void som_fwd(const float* __restrict__ x,
                                               const float* __restrict__ saug,
                                               float* __restrict__ feat) {
    __shared__ float sm[NCELL * CKP];          // 28 KiB
    const int tid = threadIdx.x;
    const int b   = blockIdx.x;

    // coalesced LDS fill: 7168 floats = 28 per thread
    #pragma unroll
    for (int j = 0; j < CKP; ++j) sm[tid + j * 256] = saug[tid + j * 256];
    __syncthreads();

    if (tid < NPATCH) {
        const int oi = tid / NOUT, oj = tid % NOUT;
        const float* xb = x + (size_t)b * (3 * 32 * 32) + (2 * oi) * 32 + (2 * oj);
        float p[CKP];
        #pragma unroll
        for (int c = 0; c < 3; ++c)
            #pragma unroll
            for (int kh = 0; kh < 3; ++kh)
                #pragma unroll
                for (int kw = 0; kw < 3; ++kw)
                    p[c * 9 + kh * 3 + kw] = xb[c * 1024 + kh * 32 + kw];
        p[CK] = -1.0f;   // folds the -0.5|s|^2 term into the dot product

        float best = -1e30f;
        int   bidx = 0;
        for (int c = 0; c < NCELL; ++c) {
            const float* sr = &sm[c * CKP];
            float a0 = 0.f, a1 = 0.f, a2 = 0.f, a3 = 0.f;
            #pragma unroll
            for (int k = 0; k < 7; ++k) {     // 28 = 7 x 4, 4 chains for ILP
                a0 = fmaf(p[4 * k + 0], sr[4 * k + 0], a0);
                a1 = fmaf(p[4 * k + 1], sr[4 * k + 1], a1);
                a2 = fmaf(p[4 * k + 2], sr[4 * k + 2], a2);
                a3 = fmaf(p[4 * k + 3], sr[4 * k + 3], a3);
            }
            float acc = (a0 + a1) + (a2 + a3);
            if (acc > best) { best = acc; bidx = c; }
        }
        // winner -> normalized grid coords; feat layout [b][2][15][15] flattened
        feat[(size_t)b * FEATDIM + tid]          = (float)(bidx >> 4) * 0.0625f;
        feat[(size_t)b * FEATDIM + NPATCH + tid] = (float)(bidx & 15) * 0.0625f;
    }
}

// ---------------------------------------------------------------------------
// Kernel 3: generic f32 GEMM  out = act(A @ W^T + bias)
// A [M][K] row-major, W [N][K] row-major, out [M][N]. 64x64 tile, BK=16,
// 256 threads, 4x4 micro-tile per thread.
// ---------------------------------------------------------------------------
template <int RELU>
__global__ __launch_bounds__(256) void mlp_gemm(const float* __restrict__ A,
                                                const float* __restrict__ Wt,
                                                const float* __restrict__ bias,
                                                float* __restrict__ out,
                                                int M, int N, int K) {
    __shared__ float As[16][68];   // [k][m], padded stride 68 (16B-aligned rows, 2-way max)
    __shared__ float Bs[16][68];   // [k][n]

    const int tid = threadIdx.x;
    const int m0 = blockIdx.y * 64;
    const int n0 = blockIdx.x * 64;
    const int tn = tid & 15, tm = tid >> 4;
    const int rA = tid >> 2, kq = tid & 3;     // staging: row rA, k-quad kq

    float acc[4][4];
    #pragma unroll
    for (int i = 0; i < 4; ++i)
        #pragma unroll
        for (int j = 0; j < 4; ++j) acc[i][j] = 0.f;

    for (int k0 = 0; k0 < K; k0 += 16) {
        #pragma unroll
        for (int j = 0; j < 4; ++j) {
            int k = k0 + kq * 4 + j;
            As[kq * 4 + j][rA] = (k < K) ? A[(size_t)(m0 + rA) * K + k] : 0.f;
            int n = n0 + rA;
            Bs[kq * 4 + j][rA] = (k < K && n < N) ? Wt[(size_t)n * K + k] : 0.f;
        }
        __syncthreads();
        #pragma unroll
        for (int k = 0; k < 16; ++k) {
            float a[4], w[4];
            #pragma unroll
            for (int i = 0; i < 4; ++i) a[i] = As[k][tm * 4 + i];
            #pragma unroll
            for (int j = 0; j < 4; ++j) w[j] = Bs[k][tn * 4 + j];
            #pragma unroll
            for (int i = 0; i < 4; ++i)
                #pragma unroll
                for (int j = 0; j < 4; ++j) acc[i][j] = fmaf(a[i], w[j], acc[i][j]);
        }
        __syncthreads();
    }

    #pragma unroll
    for (int i = 0; i < 4; ++i) {
        int m = m0 + tm * 4 + i;
        #pragma unroll
        for (int j = 0; j < 4; ++j) {
            int n = n0 + tn * 4 + j;
            if (n < N) {
                float v = acc[i][j] + bias[n];
                if (RELU) v = fmaxf(v, 0.f);
                out[(size_t)m * N + n] = v;
            }
        }
    }
}

// ---------------------------------------------------------------------------
extern "C" void kernel_launch(void* const* d_in, const int* in_sizes, int n_in,
                              void* d_out, int out_size, void* d_ws, size_t ws_size,
                              hipStream_t stream) {
    const float* x   = (const float*)d_in[0];  // [2048,3,32,32]
    const float* som = (const float*)d_in[1];  // [16,16,3,3,3]
    const float* W1  = (const float*)d_in[2];  // [400,450]
    const float* b1  = (const float*)d_in[3];
    const float* W2  = (const float*)d_in[4];  // [200,400]
    const float* b2  = (const float*)d_in[5];
    const float* W3  = (const float*)d_in[6];  // [100,200]
    const float* b3  = (const float*)d_in[7];
    const float* W4  = (const float*)d_in[8];  // [10,100]
    const float* b4  = (const float*)d_in[9];
    // d_in[10] = som_coef (unused in forward)

    float* ws = (float*)d_ws;
    float* saug = ws;                               // 256*28      = 7,168
    float* feat = ws + 8192;                        // 2048*450    = 921,600
    float* h1   = feat + (size_t)BATCH * FEATDIM;   // 2048*400
    float* h2   = h1 + (size_t)BATCH * 400;         // 2048*200
    float* h3   = h2 + (size_t)BATCH * 200;         // 2048*100
    float* outp = (float*)d_out;                    // [2048,10]

    prep_som<<<1, 256, 0, stream>>>(som, saug);
    som_fwd<<<BATCH, 256, 0, stream>>>(x, saug, feat);

    dim3 blk(256);
    mlp_gemm<1><<<dim3((400 + 63) / 64, BATCH / 64), blk, 0, stream>>>(feat, W1, b1, h1, BATCH, 400, FEATDIM);
    mlp_gemm<1><<<dim3((200 + 63) / 64, BATCH / 64), blk, 0, stream>>>(h1, W2, b2, h2, BATCH, 200, 400);
    mlp_gemm<1><<<dim3((100 + 63) / 64, BATCH / 64), blk, 0, stream>>>(h2, W3, b3, h3, BATCH, 100, 200);
    mlp_gemm<0><<<dim3(1, BATCH / 64), blk, 0, stream>>>(h3, W4, b4, outp, BATCH, 10, 100);
}

// Round 3
// 246.815 us; speedup vs baseline: 1.4379x; 1.4379x over previous
//
#include <hip/hip_runtime.h>
#include <hip/hip_bf16.h>

#define NOUT    15
#define NPATCH  225
#define BATCH   2048
#define FEATDIM 450
#define NPTOT   (BATCH * NPATCH)   // 460800 patches, 7200 blocks of 64

// per-cell layout: 4 k-chunks x {hi8, mid8, lo8} = 96 shorts, padded to 104
// (208 B cell stride -> 2-way max LDS bank alias across the 16 col-lanes)
#define CELLSTR 104
#define SBYTES  (256 * CELLSTR * 2)   // 53,248

typedef __attribute__((ext_vector_type(4))) float f32x4;
typedef __attribute__((ext_vector_type(2))) float f32x2;
typedef __attribute__((ext_vector_type(8))) short bf16x8s;

static __device__ __forceinline__ short bf2s(__hip_bfloat16 h) {
    union { __hip_bfloat16 b; short s; } u; u.b = h; return u.s;
}

// ---------------------------------------------------------------------------
// prep: SOM cells -> exact triple-split bf16 fragments + f32 half-norm bias.
// v = h + m + l exactly (24-bit significand coverage).
// ---------------------------------------------------------------------------
__global__ void prep_som(const float* __restrict__ som,
                         short* __restrict__ sbuf, float* __restrict__ sbias) {
    int c = threadIdx.x;               // 256 cells, one thread each
    float s2 = 0.f;
    #pragma unroll
    for (int kc = 0; kc < 4; ++kc)
        #pragma unroll
        for (int j = 0; j < 8; ++j) {
            int k = kc * 8 + j;
            float v = (k < 27) ? som[c * 27 + k] : 0.f;
            __hip_bfloat16 h = __float2bfloat16(v);
            float r1 = v - __bfloat162float(h);
            __hip_bfloat16 m = __float2bfloat16(r1);
            float r2 = r1 - __bfloat162float(m);
            __hip_bfloat16 l = __float2bfloat16(r2);
            sbuf[c * CELLSTR + kc * 24 + j]      = bf2s(h);
            sbuf[c * CELLSTR + kc * 24 + 8 + j]  = bf2s(m);
            sbuf[c * CELLSTR + kc * 24 + 16 + j] = bf2s(l);
            if (k < 27) s2 = fmaf(v, v, s2);
        }
    sbias[c] = 0.5f * s2;
}

// ---------------------------------------------------------------------------
// SOM forward via MFMA, 6-term triple-split product (error ~5e-7 << ref's
// own f32 rounding). score = p.s - 0.5|s|^2; argmax == argmin dist; strict >
// over ascending ct + min-index cross-lane tie-break = first-occurrence.
// ---------------------------------------------------------------------------
__global__ __launch_bounds__(256) void som_mfma(const float* __restrict__ x,
                                                const short* __restrict__ sbuf,
                                                const float* __restrict__ sbias,
                                                float* __restrict__ feat) {
    __shared__ short SB[256 * CELLSTR];   // 53,248 B
    __shared__ float Sb[256];

    const int tid = threadIdx.x;
    {   // cooperative fill: 3328 uint4 = 13 per thread
        const uint4* g = (const uint4*)sbuf;
        uint4* l = (uint4*)SB;
        #pragma unroll
        for (int i = 0; i < 13; ++i) l[tid + i * 256] = g[tid + i * 256];
        Sb[tid] = sbias[tid];
    }
    __syncthreads();

    const int wv   = tid >> 6;
    const int lane = tid & 63;
    const int row  = lane & 15;
    const int kc   = lane >> 4;        // k-chunk 0..3
    const int col  = lane & 15;        // C/D column within tile

    // ---- A fragment: gather 8 patch elements, exact triple split ----
    unsigned gp = blockIdx.x * 64u + wv * 16u + row;
    unsigned b  = gp / 225u;
    unsigned t  = gp - b * 225u;
    unsigned oi = t / 15u, oj = t - oi * 15u;
    const float* xb = x + (size_t)b * 3072 + oi * 64 + oj * 2;

    bf16x8s ah, am, al;
    #pragma unroll
    for (int j = 0; j < 8; ++j) {
        int k = kc * 8 + j;
        float v = 0.f;
        if (k < 27) {
            int c = k / 9, rr = k - c * 9;
            int kh = rr / 3, kw = rr - kh * 3;
            v = xb[c * 1024 + kh * 32 + kw];
        }
        __hip_bfloat16 h = __float2bfloat16(v);
        float r1 = v - __bfloat162float(h);
        __hip_bfloat16 mm = __float2bfloat16(r1);
        float r2 = r1 - __bfloat162float(mm);
        ah[j] = bf2s(h);
        am[j] = bf2s(mm);
        al[j] = bf2s(__float2bfloat16(r2));
    }

    // ---- 16 column tiles of 16 cells ----
    f32x4 best = {-1e30f, -1e30f, -1e30f, -1e30f};
    int bidx[4] = {0, 0, 0, 0};
    #pragma unroll
    for (int ct = 0; ct < 16; ++ct) {
        const int cell = ct * 16 + col;
        const bf16x8s* bp = (const bf16x8s*)&SB[cell * CELLSTR + kc * 24];
        bf16x8s bh = bp[0];
        bf16x8s bm = bp[1];
        bf16x8s bl = bp[2];
        float nb = -Sb[cell];
        // two independent 3-deep chains for ILP, summed at the end
        f32x4 accA = {nb, nb, nb, nb};
        f32x4 accB = {0.f, 0.f, 0.f, 0.f};
        accA = __builtin_amdgcn_mfma_f32_16x16x32_bf16(al, bh, accA, 0, 0, 0);
        accB = __builtin_amdgcn_mfma_f32_16x16x32_bf16(ah, bl, accB, 0, 0, 0);
        accA = __builtin_amdgcn_mfma_f32_16x16x32_bf16(am, bm, accA, 0, 0, 0);
        accB = __builtin_amdgcn_mfma_f32_16x16x32_bf16(am, bh, accB, 0, 0, 0);
        accA = __builtin_amdgcn_mfma_f32_16x16x32_bf16(ah, bm, accA, 0, 0, 0);
        accB = __builtin_amdgcn_mfma_f32_16x16x32_bf16(ah, bh, accB, 0, 0, 0);
        #pragma unroll
        for (int i = 0; i < 4; ++i) {
            float sc = accA[i] + accB[i];
            bool g = sc > best[i];              // strict >: lowest ct wins
            best[i] = g ? sc   : best[i];
            bidx[i] = g ? cell : bidx[i];
        }
    }

    // ---- cross-lane argmax over the 16 columns (min-index tie-break) ----
    #pragma unroll
    for (int m = 1; m < 16; m <<= 1) {
        #pragma unroll
        for (int i = 0; i < 4; ++i) {
            float ob = __shfl_xor(best[i], m, 64);
            int   oi2 = __shfl_xor(bidx[i], m, 64);
            if (ob > best[i] || (ob == best[i] && oi2 < bidx[i])) {
                best[i] = ob; bidx[i] = oi2;
            }
        }
    }

    // ---- write winners: lane col==0 of each kc group; rows kc*4+i ----
    if (col == 0) {
        #pragma unroll
        for (int i = 0; i < 4; ++i) {
            unsigned gp2 = blockIdx.x * 64u + wv * 16u + kc * 4u + i;
            unsigned b2  = gp2 / 225u;
            unsigned t2  = gp2 - b2 * 225u;
            feat[(size_t)b2 * FEATDIM + t2]          = (float)(bidx[i] >> 4) * 0.0625f;
            feat[(size_t)b2 * FEATDIM + NPATCH + t2] = (float)(bidx[i] & 15) * 0.0625f;
        }
    }
}

// ---------------------------------------------------------------------------
// f32 GEMM out = act(A @ W^T + b). 64x64 tile, BK=32, 256 threads, 4x4 micro,
// float2 staging + register-prefetch double buffer, b128 LDS fragment reads.
// ---------------------------------------------------------------------------
template <int RELU>
__global__ __launch_bounds__(256) void mlp_gemm(const float* __restrict__ A,
                                                const float* __restrict__ Wt,
                                                const float* __restrict__ bias,
                                                float* __restrict__ out,
                                                int M, int N, int K) {
    __shared__ float As[32][68];
    __shared__ float Bs[32][68];

    const int tid = threadIdx.x;
    const int m0 = blockIdx.y * 64;
    const int n0 = blockIdx.x * 64;
    const int tn = tid & 15, tm = tid >> 4;
    const int rA = tid >> 2, kq = tid & 3;   // staging: row, k-octet

    const f32x2 z2 = {0.f, 0.f};
    f32x2 pa[4], pb[4];
    float acc[4][4];
    #pragma unroll
    for (int i = 0; i < 4; ++i)
        #pragma unroll
        for (int j = 0; j < 4; ++j) acc[i][j] = 0.f;

    const int nB = n0 + rA;
    const bool nOk = nB < N;
    const int iters = (K + 31) / 32;

    #pragma unroll
    for (int j = 0; j < 4; ++j) {
        int k = kq * 8 + 2 * j;
        pa[j] = (k < K) ? *(const f32x2*)&A[(size_t)(m0 + rA) * K + k] : z2;
        pb[j] = (k < K && nOk) ? *(const f32x2*)&Wt[(size_t)nB * K + k] : z2;
    }

    for (int it = 0; it < iters; ++it) {
        #pragma unroll
        for (int j = 0; j < 4; ++j) {
            As[kq * 8 + 2 * j][rA]     = pa[j].x;
            As[kq * 8 + 2 * j + 1][rA] = pa[j].y;
            Bs[kq * 8 + 2 * j][rA]     = pb[j].x;
            Bs[kq * 8 + 2 * j + 1][rA] = pb[j].y;
        }
        __syncthreads();

        if (it + 1 < iters) {                  // prefetch next tile during FMA
            int kb = (it + 1) * 32 + kq * 8;
            #pragma unroll
            for (int j = 0; j < 4; ++j) {
                int k = kb + 2 * j;
                pa[j] = (k < K) ? *(const f32x2*)&A[(size_t)(m0 + rA) * K + k] : z2;
                pb[j] = (k < K && nOk) ? *(const f32x2*)&Wt[(size_t)nB * K + k] : z2;
            }
        }

        #pragma unroll
        for (int k = 0; k < 32; ++k) {
            f32x4 a4 = *(const f32x4*)&As[k][tm * 4];
            f32x4 b4 = *(const f32x4*)&Bs[k][tn * 4];
            #pragma unroll
            for (int i = 0; i < 4; ++i)
                #pragma unroll
                for (int j = 0; j < 4; ++j)
                    acc[i][j] = fmaf(a4[i], b4[j], acc[i][j]);
        }
        __syncthreads();
    }

    #pragma unroll
    for (int i = 0; i < 4; ++i) {
        int m = m0 + tm * 4 + i;
        #pragma unroll
        for (int j = 0; j < 4; ++j) {
            int n = n0 + tn * 4 + j;
            if (n < N) {
                float v = acc[i][j] + bias[n];
                if (RELU) v = fmaxf(v, 0.f);
                out[(size_t)m * N + n] = v;
            }
        }
    }
}

// ---------------------------------------------------------------------------
extern "C" void kernel_launch(void* const* d_in, const int* in_sizes, int n_in,
                              void* d_out, int out_size, void* d_ws, size_t ws_size,
                              hipStream_t stream) {
    const float* x   = (const float*)d_in[0];
    const float* som = (const float*)d_in[1];
    const float* W1  = (const float*)d_in[2];
    const float* b1  = (const float*)d_in[3];
    const float* W2  = (const float*)d_in[4];
    const float* b2  = (const float*)d_in[5];
    const float* W3  = (const float*)d_in[6];
    const float* b3  = (const float*)d_in[7];
    const float* W4  = (const float*)d_in[8];
    const float* b4  = (const float*)d_in[9];

    char* ws = (char*)d_ws;
    short* sbuf  = (short*)ws;                      // 53,248 B
    float* sbias = (float*)(ws + SBYTES);           //  1,024 B
    float* feat  = (float*)(ws + SBYTES + 2048);    // 2048*450 f32
    float* h1 = feat + (size_t)BATCH * FEATDIM;
    float* h2 = h1 + (size_t)BATCH * 400;
    float* h3 = h2 + (size_t)BATCH * 200;
    float* outp = (float*)d_out;

    prep_som<<<1, 256, 0, stream>>>(som, sbuf, sbias);
    som_mfma<<<NPTOT / 64, 256, 0, stream>>>(x, sbuf, sbias, feat);

    mlp_gemm<1><<<dim3(7, BATCH / 64), 256, 0, stream>>>(feat, W1, b1, h1, BATCH, 400, FEATDIM);
    mlp_gemm<1><<<dim3(4, BATCH / 64), 256, 0, stream>>>(h1, W2, b2, h2, BATCH, 200, 400);
    mlp_gemm<1><<<dim3(2, BATCH / 64), 256, 0, stream>>>(h2, W3, b3, h3, BATCH, 100, 200);
    mlp_gemm<0><<<dim3(1, BATCH / 64), 256, 0, stream>>>(h3, W4, b4, outp, BATCH, 10, 100);
}

// Round 5
// 217.481 us; speedup vs baseline: 1.6319x; 1.1349x over previous
//
#include <hip/hip_runtime.h>
#include <hip/hip_bf16.h>

#define NOUT    15
#define NPATCH  225
#define BATCH   2048
#define FEATDIM 450
#define NPTOT   (BATCH * NPATCH)   // 460800 = 900 blocks x 512 patches
#define SOMBYTES 49152             // 16 ct x 3 terms x 64 chunks x 16B

typedef __attribute__((ext_vector_type(4))) float f32x4;
typedef __attribute__((ext_vector_type(2))) float f32x2;
typedef __attribute__((ext_vector_type(8))) short bf16x8s;

static __device__ __forceinline__ short bf2s(__hip_bfloat16 h) {
    union { __hip_bfloat16 b; short s; } u; u.b = h; return u.s;
}

// ---------------------------------------------------------------------------
// prep: SOM -> fragment-major LDS image. Chunk index C(ct,term,kc,col) =
// ct*192 + term*64 + kc*16 + col (16B chunks; term 0=hi,1=mid,2=lo).
// k-slot 27 carries -0.5*|s|^2 (A side supplies 1.0 there); slots 28..31 = 0.
// Triple split is exact: v = h + m + l for any f32 in [0,1).
// ---------------------------------------------------------------------------
__global__ void prep_som(const float* __restrict__ som, short* __restrict__ sbuf) {
    int c = threadIdx.x;               // 256 cells, one thread each
    int ct = c >> 4, col = c & 15;
    float s2 = 0.f;
    #pragma unroll
    for (int k = 0; k < 27; ++k) { float v = som[c * 27 + k]; s2 = fmaf(v, v, s2); }
    float bias = -0.5f * s2;
    #pragma unroll
    for (int kc = 0; kc < 4; ++kc)
        #pragma unroll
        for (int j = 0; j < 8; ++j) {
            int k = kc * 8 + j;
            float v = (k < 27) ? som[c * 27 + k] : ((k == 27) ? bias : 0.f);
            __hip_bfloat16 h = __float2bfloat16(v);
            float r1 = v - __bfloat162float(h);
            __hip_bfloat16 m = __float2bfloat16(r1);
            float r2 = r1 - __bfloat162float(m);
            int base = (ct * 192 + kc * 16 + col) * 8 + j;   // term stride = 512 shorts
            sbuf[base]        = bf2s(h);
            sbuf[base + 512]  = bf2s(m);
            sbuf[base + 1024] = bf2s(__float2bfloat16(r2));
        }
}

// ---------------------------------------------------------------------------
// SOM forward. 1024-thread blocks (16 waves share one 48KB LDS table), each
// wave owns 32 patches (2 A-sets sharing every B ds_read). Wave-lane roles:
// row/col = lane&15, kc = lane>>4. B reads are 64 consecutive 16B chunks
// (addr = lane*16 + immediate) -> bank-conflict-free by construction.
// ---------------------------------------------------------------------------
__global__ __launch_bounds__(1024, 4) void som_mfma(const float* __restrict__ x,
                                                    const short* __restrict__ sbuf,
                                                    float* __restrict__ feat) {
    __shared__ short SB[SOMBYTES / 2];

    const int tid = threadIdx.x;
    {   // cooperative fill: 3072 uint4, 3 per thread
        const uint4* g = (const uint4*)sbuf;
        uint4* l = (uint4*)SB;
        #pragma unroll
        for (int i = 0; i < 3; ++i) l[tid + i * 1024] = g[tid + i * 1024];
    }

    const int wv   = tid >> 6;
    const int lane = tid & 63;
    const int row  = lane & 15;
    const int kc   = lane >> 4;
    const int col  = lane & 15;

    // ---- two A-sets: gather 8 patch elements each, exact triple split ----
    bf16x8s ah[2], am[2], al[2];
    #pragma unroll
    for (int s = 0; s < 2; ++s) {
        unsigned gp = blockIdx.x * 512u + wv * 32u + s * 16u + row;
        unsigned b  = gp / 225u;
        unsigned t  = gp - b * 225u;
        unsigned oi = t / 15u, oj = t - oi * 15u;
        const float* xb = x + (size_t)b * 3072 + oi * 64 + oj * 2;
        #pragma unroll
        for (int j = 0; j < 8; ++j) {
            int k = kc * 8 + j;
            float v = 0.f;
            if (k < 27) {
                int c = k / 9, rr = k - c * 9;
                int kh = rr / 3, kw = rr - kh * 3;
                v = xb[c * 1024 + kh * 32 + kw];
            } else if (k == 27) {
                v = 1.0f;                       // bias slot
            }
            __hip_bfloat16 h = __float2bfloat16(v);
            float r1 = v - __bfloat162float(h);
            __hip_bfloat16 mm = __float2bfloat16(r1);
            float r2 = r1 - __bfloat162float(mm);
            ah[s][j] = bf2s(h);
            am[s][j] = bf2s(mm);
            al[s][j] = bf2s(__float2bfloat16(r2));
        }
    }
    __syncthreads();

    const bf16x8s* SBC = (const bf16x8s*)SB;    // 16B chunk array

    f32x4 best[2];
    int   bidx[2][4];
    #pragma unroll
    for (int s = 0; s < 2; ++s) {
        best[s] = (f32x4){-1e30f, -1e30f, -1e30f, -1e30f};
        #pragma unroll
        for (int i = 0; i < 4; ++i) bidx[s][i] = 0;
    }

    #pragma unroll
    for (int ct = 0; ct < 16; ++ct) {
        bf16x8s bh = SBC[ct * 192 + lane];           // term 0 (hi)
        bf16x8s bm = SBC[ct * 192 + 64 + lane];      // term 1 (mid)
        bf16x8s bl = SBC[ct * 192 + 128 + lane];     // term 2 (lo)
        #pragma unroll
        for (int s = 0; s < 2; ++s) {
            f32x4 accA = {0.f, 0.f, 0.f, 0.f};
            f32x4 accB = {0.f, 0.f, 0.f, 0.f};
            accA = __builtin_amdgcn_mfma_f32_16x16x32_bf16(al[s], bh, accA, 0, 0, 0);
            accB = __builtin_amdgcn_mfma_f32_16x16x32_bf16(ah[s], bl, accB, 0, 0, 0);
            accA = __builtin_amdgcn_mfma_f32_16x16x32_bf16(am[s], bm, accA, 0, 0, 0);
            accB = __builtin_amdgcn_mfma_f32_16x16x32_bf16(am[s], bh, accB, 0, 0, 0);
            accA = __builtin_amdgcn_mfma_f32_16x16x32_bf16(ah[s], bm, accA, 0, 0, 0);
            accB = __builtin_amdgcn_mfma_f32_16x16x32_bf16(ah[s], bh, accB, 0, 0, 0);
            #pragma unroll
            for (int i = 0; i < 4; ++i) {
                float sc = accA[i] + accB[i];
                bool g = sc > best[s][i];            // strict >: lowest ct wins
                best[s][i] = g ? sc : best[s][i];
                bidx[s][i] = g ? (ct * 16 + col) : bidx[s][i];
            }
        }
    }

    // ---- cross-lane argmax over the 16 cols (min-index tie-break) ----
    #pragma unroll
    for (int m = 1; m < 16; m <<= 1) {
        #pragma unroll
        for (int s = 0; s < 2; ++s)
            #pragma unroll
            for (int i = 0; i < 4; ++i) {
                float ob = __shfl_xor(best[s][i], m, 64);
                int   oi2 = __shfl_xor(bidx[s][i], m, 64);
                if (ob > best[s][i] || (ob == best[s][i] && oi2 < bidx[s][i])) {
                    best[s][i] = ob; bidx[s][i] = oi2;
                }
            }
    }

    if (col == 0) {
        #pragma unroll
        for (int s = 0; s < 2; ++s)
            #pragma unroll
            for (int i = 0; i < 4; ++i) {
                unsigned gp2 = blockIdx.x * 512u + wv * 32u + s * 16u + kc * 4u + i;
                unsigned b2  = gp2 / 225u;
                unsigned t2  = gp2 - b2 * 225u;
                feat[(size_t)b2 * FEATDIM + t2]          = (float)(bidx[s][i] >> 4) * 0.0625f;
                feat[(size_t)b2 * FEATDIM + NPATCH + t2] = (float)(bidx[s][i] & 15) * 0.0625f;
            }
    }
}

// ---------------------------------------------------------------------------
// f32 GEMM out = act(A @ W^T + b). 32x64 tile, BK=32, 128 threads, 4x4 micro,
// f32x2 staging (rows only 8B-aligned at K=450) + register-prefetch dbuf.
// Per-output FMA order: k ascending, bias at end (bit-identical to round 3).
// ---------------------------------------------------------------------------
template <int RELU>
__global__ __launch_bounds__(128) void mlp_gemm(const float* __restrict__ A,
                                                const float* __restrict__ Wt,
                                                const float* __restrict__ bias,
                                                float* __restrict__ out,
                                                int M, int N, int K) {
    __shared__ float As[32][34];
    __shared__ float Bs[32][66];

    const int tid = threadIdx.x;
    const int m0 = blockIdx.y * 32;
    const int n0 = blockIdx.x * 64;
    const int tn = tid & 15, tm = tid >> 4;        // micro-tile coords
    const int mA = tid & 31, ko = tid >> 5;        // A staging: row, k-octet (0..3)
    const int nB = tid & 63, kh = tid >> 6;        // B staging: row, k-half (0..1)

    const f32x2 z2 = {0.f, 0.f};
    f32x2 pa[4], pb[8];
    float acc[4][4];
    #pragma unroll
    for (int i = 0; i < 4; ++i)
        #pragma unroll
        for (int j = 0; j < 4; ++j) acc[i][j] = 0.f;

    const bool nOk = (n0 + nB) < N;
    const int iters = (K + 31) / 32;

    #pragma unroll
    for (int q = 0; q < 4; ++q) {
        int k = ko * 8 + 2 * q;
        pa[q] = (k < K) ? *(const f32x2*)&A[(size_t)(m0 + mA) * K + k] : z2;
    }
    #pragma unroll
    for (int q = 0; q < 8; ++q) {
        int k = kh * 16 + 2 * q;
        pb[q] = (k < K && nOk) ? *(const f32x2*)&Wt[(size_t)(n0 + nB) * K + k] : z2;
    }

    for (int it = 0; it < iters; ++it) {
        #pragma unroll
        for (int q = 0; q < 4; ++q) {
            As[ko * 8 + 2 * q][mA]     = pa[q].x;
            As[ko * 8 + 2 * q + 1][mA] = pa[q].y;
        }
        #pragma unroll
        for (int q = 0; q < 8; ++q) {
            Bs[kh * 16 + 2 * q][nB]     = pb[q].x;
            Bs[kh * 16 + 2 * q + 1][nB] = pb[q].y;
        }
        __syncthreads();

        if (it + 1 < iters) {
            int kb = (it + 1) * 32;
            #pragma unroll
            for (int q = 0; q < 4; ++q) {
                int k = kb + ko * 8 + 2 * q;
                pa[q] = (k < K) ? *(const f32x2*)&A[(size_t)(m0 + mA) * K + k] : z2;
            }
            #pragma unroll
            for (int q = 0; q < 8; ++q) {
                int k = kb + kh * 16 + 2 * q;
                pb[q] = (k < K && nOk) ? *(const f32x2*)&Wt[(size_t)(n0 + nB) * K + k] : z2;
            }
        }

        #pragma unroll
        for (int k = 0; k < 32; ++k) {
            f32x4 a4 = *(const f32x4*)&As[k][tm * 4];
            f32x4 b4 = *(const f32x4*)&Bs[k][tn * 4];
            #pragma unroll
            for (int i = 0; i < 4; ++i)
                #pragma unroll
                for (int j = 0; j < 4; ++j)
                    acc[i][j] = fmaf(a4[i], b4[j], acc[i][j]);
        }
        __syncthreads();
    }

    #pragma unroll
    for (int i = 0; i < 4; ++i) {
        int m = m0 + tm * 4 + i;
        #pragma unroll
        for (int j = 0; j < 4; ++j) {
            int n = n0 + tn * 4 + j;
            if (n < N) {
                float v = acc[i][j] + bias[n];
                if (RELU) v = fmaxf(v, 0.f);
                out[(size_t)m * N + n] = v;
            }
        }
    }
}

// ---------------------------------------------------------------------------
// L4: thread-per-output (2048x10, K=100). k-ascending FMA + bias at end.
// ---------------------------------------------------------------------------
__global__ __launch_bounds__(256) void l4_kernel(const float* __restrict__ h3,
                                                 const float* __restrict__ W4,
                                                 const float* __restrict__ b4,
                                                 float* __restrict__ out) {
    int g = blockIdx.x * 256 + threadIdx.x;
    if (g >= BATCH * 10) return;
    int m = g / 10, n = g - m * 10;
    const f32x4* a = (const f32x4*)&h3[m * 100];
    const f32x4* w = (const f32x4*)&W4[n * 100];
    float acc = 0.f;
    #pragma unroll
    for (int i = 0; i < 25; ++i) {
        f32x4 av = a[i], wv = w[i];
        acc = fmaf(av.x, wv.x, acc);
        acc = fmaf(av.y, wv.y, acc);
        acc = fmaf(av.z, wv.z, acc);
        acc = fmaf(av.w, wv.w, acc);
    }
    out[g] = acc + b4[n];
}

// ---------------------------------------------------------------------------
extern "C" void kernel_launch(void* const* d_in, const int* in_sizes, int n_in,
                              void* d_out, int out_size, void* d_ws, size_t ws_size,
                              hipStream_t stream) {
    const float* x   = (const float*)d_in[0];
    const float* som = (const float*)d_in[1];
    const float* W1  = (const float*)d_in[2];
    const float* b1  = (const float*)d_in[3];
    const float* W2  = (const float*)d_in[4];
    const float* b2  = (const float*)d_in[5];
    const float* W3  = (const float*)d_in[6];
    const float* b3  = (const float*)d_in[7];
    const float* W4  = (const float*)d_in[8];
    const float* b4  = (const float*)d_in[9];

    char* ws = (char*)d_ws;
    short* sbuf = (short*)ws;                       // 49,152 B
    float* feat = (float*)(ws + SOMBYTES);          // 2048*450 f32
    float* h1 = feat + (size_t)BATCH * FEATDIM;
    float* h2 = h1 + (size_t)BATCH * 400;
    float* h3 = h2 + (size_t)BATCH * 200;
    float* outp = (float*)d_out;

    prep_som<<<1, 256, 0, stream>>>(som, sbuf);
    som_mfma<<<NPTOT / 512, 1024, 0, stream>>>(x, sbuf, feat);

    mlp_gemm<1><<<dim3(7, BATCH / 32), 128, 0, stream>>>(feat, W1, b1, h1, BATCH, 400, FEATDIM);
    mlp_gemm<1><<<dim3(4, BATCH / 32), 128, 0, stream>>>(h1, W2, b2, h2, BATCH, 200, 400);
    mlp_gemm<1><<<dim3(2, BATCH / 32), 128, 0, stream>>>(h2, W3, b3, h3, BATCH, 100, 200);
    l4_kernel<<<80, 256, 0, stream>>>(h3, W4, b4, outp);
}

// Round 8
// 195.261 us; speedup vs baseline: 1.8176x; 1.1138x over previous
//
#include <hip/hip_runtime.h>

#define BATCH   2048
#define NPATCH  225
#define NPTOT   (BATCH * NPATCH)   // 460800 = 900 blocks x 512 patches
#define FKP     480                // feat padded K (450 + bias + pad)
#define SOMBYTES 49152             // 16 ct x 3 terms x 64 chunks x 16B

typedef __attribute__((ext_vector_type(4))) float f32x4;
typedef __attribute__((ext_vector_type(8))) short bf16x8s;

// exact truncation split: v = h + m + l with h,m,l all bf16-representable.
// h = top 16 bits of v; residuals have <=16 / <=8 significant bits -> exact.
__device__ __forceinline__ void tsplit(float v, unsigned short& h,
                                       unsigned short& m, unsigned short& l) {
    unsigned bv = __float_as_uint(v);
    h = (unsigned short)(bv >> 16);
    float r1 = v - __uint_as_float(bv & 0xFFFF0000u);
    unsigned br = __float_as_uint(r1);
    m = (unsigned short)(br >> 16);
    float r2 = r1 - __uint_as_float(br & 0xFFFF0000u);
    l = (unsigned short)(__float_as_uint(r2) >> 16);
}

// 6-term split product, chained into one accumulator (small terms first)
__device__ __forceinline__ f32x4 mm6(bf16x8s Ah, bf16x8s Am, bf16x8s Al,
                                     bf16x8s Wh, bf16x8s Wm, bf16x8s Wl, f32x4 a) {
    a = __builtin_amdgcn_mfma_f32_16x16x32_bf16(Al, Wh, a, 0, 0, 0);
    a = __builtin_amdgcn_mfma_f32_16x16x32_bf16(Ah, Wl, a, 0, 0, 0);
    a = __builtin_amdgcn_mfma_f32_16x16x32_bf16(Am, Wm, a, 0, 0, 0);
    a = __builtin_amdgcn_mfma_f32_16x16x32_bf16(Am, Wh, a, 0, 0, 0);
    a = __builtin_amdgcn_mfma_f32_16x16x32_bf16(Ah, Wm, a, 0, 0, 0);
    a = __builtin_amdgcn_mfma_f32_16x16x32_bf16(Ah, Wh, a, 0, 0, 0);
    return a;
}

// ---------------------------------------------------------------------------
// prep_som: SOM -> fragment-major split image (same layout as round 5).
// chunk(ct,term,kc,col) = ct*192 + term*64 + kc*16 + col (16B chunks).
// k-slot 27 = -0.5*|s|^2 (A supplies exact 1.0 there); 28..31 = 0.
// ---------------------------------------------------------------------------
__global__ void prep_som(const float* __restrict__ som, short* __restrict__ sbuf) {
    int c = threadIdx.x;
    int ct = c >> 4, col = c & 15;
    float s2 = 0.f;
    #pragma unroll
    for (int k = 0; k < 27; ++k) { float v = som[c * 27 + k]; s2 = fmaf(v, v, s2); }
    float bias = -0.5f * s2;
    #pragma unroll
    for (int kc = 0; kc < 4; ++kc)
        #pragma unroll
        for (int j = 0; j < 8; ++j) {
            int k = kc * 8 + j;
            float v = (k < 27) ? som[c * 27 + k] : ((k == 27) ? bias : 0.f);
            unsigned short h, m, l;
            tsplit(v, h, m, l);
            int base = (ct * 192 + kc * 16 + col) * 8 + j;
            sbuf[base]        = (short)h;
            sbuf[base + 512]  = (short)m;
            sbuf[base + 1024] = (short)l;
        }
}

// ---------------------------------------------------------------------------
// prep_w: weights -> fragment-major split form, bias folded at k-slot K.
// Layout per layer: [tile = nt*KC+kc][term][chunk 0..63][8 shorts].
// Also fills feat k-pad (slot 450 = 1.0, 451..479 = 0).
// ---------------------------------------------------------------------------
__global__ __launch_bounds__(256) void prep_w(
        const float* __restrict__ W1, const float* __restrict__ b1,
        const float* __restrict__ W2, const float* __restrict__ b2,
        const float* __restrict__ W3, const float* __restrict__ b3,
        const float* __restrict__ W4, const float* __restrict__ b4,
        short* __restrict__ wf1, short* __restrict__ wf2,
        short* __restrict__ wf3, short* __restrict__ wf4,
        unsigned short* __restrict__ featbf) {
    int id = blockIdx.x * 256 + threadIdx.x;
    const float* W; const float* b; short* o; int N, K, tile, ch;
    if (id < 24000) {                 // W1: 375 tiles (25 nt x 15 kc)
        tile = id >> 6; ch = id & 63; W = W1; b = b1; N = 400; K = 450;
        o = wf1 + (size_t)tile * 1536 + ch * 8;
        int kc = tile % 15, nt = tile / 15;
        int n = nt * 16 + (ch & 15), oct = ch >> 4;
        #pragma unroll
        for (int j = 0; j < 8; ++j) {
            int k = kc * 32 + oct * 8 + j;
            float v = 0.f;
            if (n < N) { if (k < K) v = W[n * K + k]; else if (k == K) v = b[n]; }
            unsigned short h, m, l; tsplit(v, h, m, l);
            o[j] = (short)h; o[512 + j] = (short)m; o[1024 + j] = (short)l;
        }
    } else if (id < 34816) {          // W2: 169 tiles (13 nt x 13 kc)
        int id2 = id - 24000; tile = id2 >> 6; ch = id2 & 63; N = 200; K = 400;
        o = wf2 + (size_t)tile * 1536 + ch * 8;
        int kc = tile % 13, nt = tile / 13;
        int n = nt * 16 + (ch & 15), oct = ch >> 4;
        #pragma unroll
        for (int j = 0; j < 8; ++j) {
            int k = kc * 32 + oct * 8 + j;
            float v = 0.f;
            if (n < N) { if (k < K) v = W2[n * K + k]; else if (k == K) v = b2[n]; }
            unsigned short h, m, l; tsplit(v, h, m, l);
            o[j] = (short)h; o[512 + j] = (short)m; o[1024 + j] = (short)l;
        }
    } else if (id < 37952) {          // W3: 49 tiles (7 nt x 7 kc)
        int id2 = id - 34816; tile = id2 >> 6; ch = id2 & 63; N = 100; K = 200;
        o = wf3 + (size_t)tile * 1536 + ch * 8;
        int kc = tile % 7, nt = tile / 7;
        int n = nt * 16 + (ch & 15), oct = ch >> 4;
        #pragma unroll
        for (int j = 0; j < 8; ++j) {
            int k = kc * 32 + oct * 8 + j;
            float v = 0.f;
            if (n < N) { if (k < K) v = W3[n * K + k]; else if (k == K) v = b3[n]; }
            unsigned short h, m, l; tsplit(v, h, m, l);
            o[j] = (short)h; o[512 + j] = (short)m; o[1024 + j] = (short)l;
        }
    } else if (id < 38208) {          // W4: 4 tiles (1 nt x 4 kc)
        int id2 = id - 37952; tile = id2 >> 6; ch = id2 & 63; N = 10; K = 100;
        o = wf4 + (size_t)tile * 1536 + ch * 8;
        int kc = tile;
        int n = ch & 15, oct = ch >> 4;
        #pragma unroll
        for (int j = 0; j < 8; ++j) {
            int k = kc * 32 + oct * 8 + j;
            float v = 0.f;
            if (n < N) { if (k < K) v = W4[n * K + k]; else if (k == K) v = b4[n]; }
            unsigned short h, m, l; tsplit(v, h, m, l);
            o[j] = (short)h; o[512 + j] = (short)m; o[1024 + j] = (short)l;
        }
    } else if (id < 40256) {          // feat k-pad: rows 0..2047
        int r = id - 38208;
        unsigned short* f = featbf + (size_t)r * FKP + 450;
        f[0] = 0x3F80;                 // 1.0 bf16 (bias slot; A side)
        #pragma unroll
        for (int j = 1; j < 30; ++j) f[j] = 0;
    }
}

// ---------------------------------------------------------------------------
// SOM forward. 512-thr blocks (8 waves share 48KB LDS table), 4 A-sets/wave
// (64 patches). Chained 6-MFMA per set (4 independent chains). Trunc-split
// A-build (int ops, exact). Winners written directly as bf16 into featbf.
// ---------------------------------------------------------------------------
__global__ __launch_bounds__(512, 4) void som_mfma(const float* __restrict__ x,
                                                   const short* __restrict__ sbuf,
                                                   unsigned short* __restrict__ featbf) {
    __shared__ short SB[SOMBYTES / 2];
    const int tid = threadIdx.x;
    {   // cooperative fill: 3072 uint4, 6 per thread
        const uint4* g = (const uint4*)sbuf;
        uint4* l = (uint4*)SB;
        #pragma unroll
        for (int i = 0; i < 6; ++i) l[tid + i * 512] = g[tid + i * 512];
    }

    const int wv   = tid >> 6;
    const int lane = tid & 63;
    const int row  = lane & 15;
    const int kc   = lane >> 4;
    const int col  = lane & 15;

    // ---- four A-sets: gather 8 patch elems each, exact trunc split ----
    bf16x8s ah[4], am[4], al[4];
    #pragma unroll
    for (int s = 0; s < 4; ++s) {
        unsigned gp = blockIdx.x * 512u + wv * 64u + s * 16u + row;
        unsigned b  = gp / 225u;
        unsigned t  = gp - b * 225u;
        unsigned oi = t / 15u, oj = t - oi * 15u;
        const float* xb = x + (size_t)b * 3072 + oi * 64 + oj * 2;
        #pragma unroll
        for (int j = 0; j < 8; ++j) {
            int k = kc * 8 + j;
            float v = 0.f;
            if (k < 27) {
                int c = k / 9, rr = k - c * 9;
                int kh = rr / 3, kw = rr - kh * 3;
                v = xb[c * 1024 + kh * 32 + kw];
            } else if (k == 27) {
                v = 1.0f;                       // bias slot (exact in bf16 hi)
            }
            unsigned short hh, mm, ll;
            tsplit(v, hh, mm, ll);
            ah[s][j] = (short)hh; am[s][j] = (short)mm; al[s][j] = (short)ll;
        }
    }
    __syncthreads();

    const bf16x8s* SBC = (const bf16x8s*)SB;

    f32x4 best[4];
    int   bidx[4][4];
    #pragma unroll
    for (int s = 0; s < 4; ++s) {
        best[s] = (f32x4){-1e30f, -1e30f, -1e30f, -1e30f};
        #pragma unroll
        for (int i = 0; i < 4; ++i) bidx[s][i] = 0;
    }

    #pragma unroll
    for (int ct = 0; ct < 16; ++ct) {
        bf16x8s bh = SBC[ct * 192 + lane];
        bf16x8s bm = SBC[ct * 192 + 64 + lane];
        bf16x8s bl = SBC[ct * 192 + 128 + lane];
        #pragma unroll
        for (int s = 0; s < 4; ++s) {
            f32x4 a = {0.f, 0.f, 0.f, 0.f};
            a = mm6(ah[s], am[s], al[s], bh, bm, bl, a);
            #pragma unroll
            for (int i = 0; i < 4; ++i) {
                bool g = a[i] > best[s][i];          // strict >: lowest ct wins
                best[s][i] = g ? a[i] : best[s][i];
                bidx[s][i] = g ? (ct * 16 + col) : bidx[s][i];
            }
        }
    }

    // ---- cross-lane argmax over the 16 cols (min-index tie-break) ----
    #pragma unroll
    for (int m = 1; m < 16; m <<= 1) {
        #pragma unroll
        for (int s = 0; s < 4; ++s)
            #pragma unroll
            for (int i = 0; i < 4; ++i) {
                float ob = __shfl_xor(best[s][i], m, 64);
                int   oi2 = __shfl_xor(bidx[s][i], m, 64);
                if (ob > best[s][i] || (ob == best[s][i] && oi2 < bidx[s][i])) {
                    best[s][i] = ob; bidx[s][i] = oi2;
                }
            }
    }

    if (col == 0) {
        #pragma unroll
        for (int s = 0; s < 4; ++s)
            #pragma unroll
            for (int i = 0; i < 4; ++i) {
                unsigned gp2 = blockIdx.x * 512u + wv * 64u + s * 16u + kc * 4u + i;
                unsigned b2  = gp2 / 225u;
                unsigned t2  = gp2 - b2 * 225u;
                float vm = (float)(bidx[s][i] >> 4) * 0.0625f;   // exact bf16
                float vn = (float)(bidx[s][i] & 15) * 0.0625f;
                featbf[(size_t)b2 * FKP + t2]       = (unsigned short)(__float_as_uint(vm) >> 16);
                featbf[(size_t)b2 * FKP + 225 + t2] = (unsigned short)(__float_as_uint(vn) >> 16);
            }
    }
}

// ---------------------------------------------------------------------------
// Fused MLP: one block = 16 batch rows, 8 waves, whole L1->L4 chain in LDS.
// Activations live in LDS in MFMA fragment-major split form; weights come
// pre-split from global (L2-resident). LDS: h1frag 39KB + h2frag 21KB = 60KB,
// h3frag aliases h1frag.
// ---------------------------------------------------------------------------
#define H1S 19968   // shorts: 3 terms * 13 kc * 512
#define H2S 10752   // shorts: 3 terms *  7 kc * 512

template <int NT, int KC, int OKC, int NVALID>
__device__ __forceinline__ void layer_mid(const short* inS, short* outS,
                                          const short* __restrict__ wf,
                                          int wv, int lane) {
    const bf16x8s* Ain = (const bf16x8s*)inS;
    const int col = lane & 15, g = lane >> 4;
    constexpr int TPW = (NT + 7) / 8;
    f32x4 acc[TPW];
    #pragma unroll
    for (int i = 0; i < TPW; ++i) acc[i] = (f32x4){0.f, 0.f, 0.f, 0.f};
    #pragma unroll
    for (int kc = 0; kc < KC; ++kc) {
        bf16x8s Ah = Ain[(0 * KC + kc) * 64 + lane];
        bf16x8s Am = Ain[(1 * KC + kc) * 64 + lane];
        bf16x8s Al = Ain[(2 * KC + kc) * 64 + lane];
        #pragma unroll
        for (int ti = 0; ti < TPW; ++ti) {
            int t = wv + ti * 8;
            if (t < NT) {
                const bf16x8s* W = (const bf16x8s*)(wf + (size_t)(t * KC + kc) * 1536);
                acc[ti] = mm6(Ah, Am, Al, W[lane], W[64 + lane], W[128 + lane], acc[ti]);
            }
        }
    }
    #pragma unroll
    for (int ti = 0; ti < TPW; ++ti) {
        int t = wv + ti * 8;
        if (t < NT) {
            int k = t * 16 + col;
            if (k < NVALID) {
                int kc2 = k >> 5, oct = (k >> 3) & 3, j = k & 7;
                #pragma unroll
                for (int i = 0; i < 4; ++i) {
                    int r = g * 4 + i;
                    float v = fmaxf(acc[ti][i], 0.f);
                    unsigned short hh, mm, ll;
                    tsplit(v, hh, mm, ll);
                    outS[((0 * OKC + kc2) * 64 + oct * 16 + r) * 8 + j] = (short)hh;
                    outS[((1 * OKC + kc2) * 64 + oct * 16 + r) * 8 + j] = (short)mm;
                    outS[((2 * OKC + kc2) * 64 + oct * 16 + r) * 8 + j] = (short)ll;
                }
            }
        }
    }
}

// pad-init helper: slots [K0, K0+NS) of a frag with OKC, bias 1.0 at K0
template <int OKC, int K0, int NS>
__device__ __forceinline__ void pad_init(short* outS, int tid) {
    for (int p = tid; p < NS * 16 * 3; p += 512) {
        int term = p / (NS * 16);
        int rem  = p % (NS * 16);
        int ks   = K0 + rem / 16;
        int r    = rem % 16;
        unsigned short v = (ks == K0 && term == 0) ? 0x3F80 : 0;
        outS[((term * OKC + (ks >> 5)) * 64 + ((ks >> 3) & 3) * 16 + r) * 8 + (ks & 7)] = (short)v;
    }
}

__global__ __launch_bounds__(512) void fused_mlp(
        const unsigned short* __restrict__ featbf,
        const short* __restrict__ wf1, const short* __restrict__ wf2,
        const short* __restrict__ wf3, const short* __restrict__ wf4,
        float* __restrict__ out) {
    __shared__ short FB[H1S + H2S];    // 61,440 B

    const int tid  = threadIdx.x;
    const int wv   = tid >> 6;
    const int lane = tid & 63;
    const int col  = lane & 15, g = lane >> 4;
    const int blk  = blockIdx.x;

    // ---- L1: A (feat, exact 1-term bf16) from global, W from wf1 ----
    const unsigned short* fb = featbf + (size_t)(blk * 16 + col) * FKP;
    bf16x8s af[15];
    #pragma unroll
    for (int kc = 0; kc < 15; ++kc)
        af[kc] = *(const bf16x8s*)(fb + kc * 32 + g * 8);

    f32x4 acc1[4];
    #pragma unroll
    for (int i = 0; i < 4; ++i) acc1[i] = (f32x4){0.f, 0.f, 0.f, 0.f};
    #pragma unroll
    for (int kc = 0; kc < 15; ++kc) {
        #pragma unroll
        for (int ti = 0; ti < 4; ++ti) {
            int t = wv + ti * 8;
            if (t < 25) {
                const bf16x8s* W = (const bf16x8s*)(wf1 + (size_t)(t * 15 + kc) * 1536);
                f32x4 a = acc1[ti];
                a = __builtin_amdgcn_mfma_f32_16x16x32_bf16(af[kc], W[128 + lane], a, 0, 0, 0);
                a = __builtin_amdgcn_mfma_f32_16x16x32_bf16(af[kc], W[64 + lane],  a, 0, 0, 0);
                a = __builtin_amdgcn_mfma_f32_16x16x32_bf16(af[kc], W[lane],       a, 0, 0, 0);
                acc1[ti] = a;
            }
        }
    }
    // write h1frag (OKC=13, N=400, relu)
    #pragma unroll
    for (int ti = 0; ti < 4; ++ti) {
        int t = wv + ti * 8;
        if (t < 25) {
            int k = t * 16 + col;
            int kc2 = k >> 5, oct = (k >> 3) & 3, j = k & 7;
            #pragma unroll
            for (int i = 0; i < 4; ++i) {
                int r = g * 4 + i;
                float v = fmaxf(acc1[ti][i], 0.f);
                unsigned short hh, mm, ll;
                tsplit(v, hh, mm, ll);
                FB[((0 * 13 + kc2) * 64 + oct * 16 + r) * 8 + j] = (short)hh;
                FB[((1 * 13 + kc2) * 64 + oct * 16 + r) * 8 + j] = (short)mm;
                FB[((2 * 13 + kc2) * 64 + oct * 16 + r) * 8 + j] = (short)ll;
            }
        }
    }
    pad_init<13, 400, 16>(FB, tid);                 // h1 pads: bias@400, 401..415=0
    __syncthreads();

    // ---- L2: h1frag -> h2frag ----
    layer_mid<13, 13, 7, 200>(FB, FB + H1S, wf2, wv, lane);
    pad_init<7, 200, 24>(FB + H1S, tid);            // h2 pads: bias@200, 201..223=0
    __syncthreads();

    // ---- L3: h2frag -> h3frag (aliases h1frag region) ----
    layer_mid<7, 7, 4, 100>(FB + H1S, FB, wf3, wv, lane);
    pad_init<4, 100, 28>(FB, tid);                  // h3 pads: bias@100, 101..127=0
    __syncthreads();

    // ---- L4: wave 0 only, write output ----
    if (wv == 0) {
        const bf16x8s* Ain = (const bf16x8s*)FB;
        f32x4 a = {0.f, 0.f, 0.f, 0.f};
        #pragma unroll
        for (int kc = 0; kc < 4; ++kc) {
            bf16x8s Ah = Ain[(0 * 4 + kc) * 64 + lane];
            bf16x8s Am = Ain[(1 * 4 + kc) * 64 + lane];
            bf16x8s Al = Ain[(2 * 4 + kc) * 64 + lane];
            const bf16x8s* W = (const bf16x8s*)(wf4 + (size_t)kc * 1536);
            a = mm6(Ah, Am, Al, W[lane], W[64 + lane], W[128 + lane], a);
        }
        if (col < 10) {
            #pragma unroll
            for (int i = 0; i < 4; ++i)
                out[(size_t)(blk * 16 + g * 4 + i) * 10 + col] = a[i];
        }
    }
}

// ---------------------------------------------------------------------------
extern "C" void kernel_launch(void* const* d_in, const int* in_sizes, int n_in,
                              void* d_out, int out_size, void* d_ws, size_t ws_size,
                              hipStream_t stream) {
    const float* x   = (const float*)d_in[0];
    const float* som = (const float*)d_in[1];
    const float* W1  = (const float*)d_in[2];
    const float* b1  = (const float*)d_in[3];
    const float* W2  = (const float*)d_in[4];
    const float* b2  = (const float*)d_in[5];
    const float* W3  = (const float*)d_in[6];
    const float* b3  = (const float*)d_in[7];
    const float* W4  = (const float*)d_in[8];
    const float* b4  = (const float*)d_in[9];

    char* ws = (char*)d_ws;
    short*          sbuf   = (short*)ws;                          //    49,152 B
    unsigned short* featbf = (unsigned short*)(ws + 49152);       // 1,966,080 B
    short*          wf1    = (short*)(ws + 2015232);              // 1,152,000 B
    short*          wf2    = (short*)(ws + 3167232);              //   519,168 B
    short*          wf3    = (short*)(ws + 3686400);              //   150,528 B
    short*          wf4    = (short*)(ws + 3836928);              //    12,288 B
    float* outp = (float*)d_out;

    prep_som<<<1, 256, 0, stream>>>(som, sbuf);
    prep_w<<<158, 256, 0, stream>>>(W1, b1, W2, b2, W3, b3, W4, b4,
                                    wf1, wf2, wf3, wf4, featbf);
    som_mfma<<<900, 512, 0, stream>>>(x, sbuf, featbf);
    fused_mlp<<<128, 512, 0, stream>>>(featbf, wf1, wf2, wf3, wf4, outp);
}

// Round 9
// 177.005 us; speedup vs baseline: 2.0051x; 1.1031x over previous
//
#include <hip/hip_runtime.h>

#define BATCH   2048
#define NPATCH  225
#define NPTOT   (BATCH * NPATCH)   // 460800 = 900 blocks x 512 patches
#define FKP     480                // feat padded K (450 + bias + pad)
#define SOMBYTES 49152             // 16 ct x 3 terms x 64 chunks x 16B

typedef __attribute__((ext_vector_type(4))) float f32x4;
typedef __attribute__((ext_vector_type(8))) short bf16x8s;

#define MFMA(A,B,C) __builtin_amdgcn_mfma_f32_16x16x32_bf16(A, B, C, 0, 0, 0)

// exact truncation split: v = h + m + l with h,m,l all bf16-representable.
__device__ __forceinline__ void tsplit(float v, unsigned short& h,
                                       unsigned short& m, unsigned short& l) {
    unsigned bv = __float_as_uint(v);
    h = (unsigned short)(bv >> 16);
    float r1 = v - __uint_as_float(bv & 0xFFFF0000u);
    unsigned br = __float_as_uint(r1);
    m = (unsigned short)(br >> 16);
    float r2 = r1 - __uint_as_float(br & 0xFFFF0000u);
    l = (unsigned short)(__float_as_uint(r2) >> 16);
}

// 6-term split product, single chain (som only — unchanged from round 8)
__device__ __forceinline__ f32x4 mm6(bf16x8s Ah, bf16x8s Am, bf16x8s Al,
                                     bf16x8s Wh, bf16x8s Wm, bf16x8s Wl, f32x4 a) {
    a = MFMA(Al, Wh, a); a = MFMA(Ah, Wl, a); a = MFMA(Am, Wm, a);
    a = MFMA(Am, Wh, a); a = MFMA(Ah, Wm, a); a = MFMA(Ah, Wh, a);
    return a;
}

// ---------------------------------------------------------------------------
// prep_all: merged weight-split + feat-pad + SOM-split (3 launches -> 1).
// Layouts identical to round 8.
// ---------------------------------------------------------------------------
__global__ __launch_bounds__(256) void prep_all(
        const float* __restrict__ som,
        const float* __restrict__ W1, const float* __restrict__ b1,
        const float* __restrict__ W2, const float* __restrict__ b2,
        const float* __restrict__ W3, const float* __restrict__ b3,
        const float* __restrict__ W4, const float* __restrict__ b4,
        short* __restrict__ sbuf,
        short* __restrict__ wf1, short* __restrict__ wf2,
        short* __restrict__ wf3, short* __restrict__ wf4,
        unsigned short* __restrict__ featbf) {
    int id = blockIdx.x * 256 + threadIdx.x;
    if (id < 24000) {                 // W1: 375 tiles (25 nt x 15 kc)
        int tile = id >> 6, ch = id & 63;
        short* o = wf1 + (size_t)tile * 1536 + ch * 8;
        int kc = tile % 15, nt = tile / 15;
        int n = nt * 16 + (ch & 15), oct = ch >> 4;
        #pragma unroll
        for (int j = 0; j < 8; ++j) {
            int k = kc * 32 + oct * 8 + j;
            float v = 0.f;
            if (n < 400) { if (k < 450) v = W1[n * 450 + k]; else if (k == 450) v = b1[n]; }
            unsigned short h, m, l; tsplit(v, h, m, l);
            o[j] = (short)h; o[512 + j] = (short)m; o[1024 + j] = (short)l;
        }
    } else if (id < 34816) {          // W2: 169 tiles (13 nt x 13 kc)
        int id2 = id - 24000, tile = id2 >> 6, ch = id2 & 63;
        short* o = wf2 + (size_t)tile * 1536 + ch * 8;
        int kc = tile % 13, nt = tile / 13;
        int n = nt * 16 + (ch & 15), oct = ch >> 4;
        #pragma unroll
        for (int j = 0; j < 8; ++j) {
            int k = kc * 32 + oct * 8 + j;
            float v = 0.f;
            if (n < 200) { if (k < 400) v = W2[n * 400 + k]; else if (k == 400) v = b2[n]; }
            unsigned short h, m, l; tsplit(v, h, m, l);
            o[j] = (short)h; o[512 + j] = (short)m; o[1024 + j] = (short)l;
        }
    } else if (id < 37952) {          // W3: 49 tiles (7 nt x 7 kc)
        int id2 = id - 34816, tile = id2 >> 6, ch = id2 & 63;
        short* o = wf3 + (size_t)tile * 1536 + ch * 8;
        int kc = tile % 7, nt = tile / 7;
        int n = nt * 16 + (ch & 15), oct = ch >> 4;
        #pragma unroll
        for (int j = 0; j < 8; ++j) {
            int k = kc * 32 + oct * 8 + j;
            float v = 0.f;
            if (n < 100) { if (k < 200) v = W3[n * 200 + k]; else if (k == 200) v = b3[n]; }
            unsigned short h, m, l; tsplit(v, h, m, l);
            o[j] = (short)h; o[512 + j] = (short)m; o[1024 + j] = (short)l;
        }
    } else if (id < 38208) {          // W4: 4 tiles (1 nt x 4 kc)
        int id2 = id - 37952, tile = id2 >> 6, ch = id2 & 63;
        short* o = wf4 + (size_t)tile * 1536 + ch * 8;
        int kc = tile;
        int n = ch & 15, oct = ch >> 4;
        #pragma unroll
        for (int j = 0; j < 8; ++j) {
            int k = kc * 32 + oct * 8 + j;
            float v = 0.f;
            if (n < 10) { if (k < 100) v = W4[n * 100 + k]; else if (k == 100) v = b4[n]; }
            unsigned short h, m, l; tsplit(v, h, m, l);
            o[j] = (short)h; o[512 + j] = (short)m; o[1024 + j] = (short)l;
        }
    } else if (id < 40256) {          // feat k-pad: rows 0..2047
        int r = id - 38208;
        unsigned short* f = featbf + (size_t)r * FKP + 450;
        f[0] = 0x3F80;                // 1.0 bf16 (bias slot; A side)
        #pragma unroll
        for (int j = 1; j < 30; ++j) f[j] = 0;
    } else if (id < 40512) {          // SOM cells: 256 threads
        int c = id - 40256;
        int ct = c >> 4, col = c & 15;
        float s2 = 0.f;
        #pragma unroll
        for (int k = 0; k < 27; ++k) { float v = som[c * 27 + k]; s2 = fmaf(v, v, s2); }
        float bias = -0.5f * s2;
        #pragma unroll
        for (int kc = 0; kc < 4; ++kc)
            #pragma unroll
            for (int j = 0; j < 8; ++j) {
                int k = kc * 8 + j;
                float v = (k < 27) ? som[c * 27 + k] : ((k == 27) ? bias : 0.f);
                unsigned short h, m, l;
                tsplit(v, h, m, l);
                int base = (ct * 192 + kc * 16 + col) * 8 + j;
                sbuf[base]        = (short)h;
                sbuf[base + 512]  = (short)m;
                sbuf[base + 1024] = (short)l;
            }
    }
}

// ---------------------------------------------------------------------------
// SOM forward — UNCHANGED from round 8 (known 66 us; serves as the ruler).
// ---------------------------------------------------------------------------
__global__ __launch_bounds__(512, 4) void som_mfma(const float* __restrict__ x,
                                                   const short* __restrict__ sbuf,
                                                   unsigned short* __restrict__ featbf) {
    __shared__ short SB[SOMBYTES / 2];
    const int tid = threadIdx.x;
    {
        const uint4* g = (const uint4*)sbuf;
        uint4* l = (uint4*)SB;
        #pragma unroll
        for (int i = 0; i < 6; ++i) l[tid + i * 512] = g[tid + i * 512];
    }

    const int wv   = tid >> 6;
    const int lane = tid & 63;
    const int row  = lane & 15;
    const int kc   = lane >> 4;
    const int col  = lane & 15;

    bf16x8s ah[4], am[4], al[4];
    #pragma unroll
    for (int s = 0; s < 4; ++s) {
        unsigned gp = blockIdx.x * 512u + wv * 64u + s * 16u + row;
        unsigned b  = gp / 225u;
        unsigned t  = gp - b * 225u;
        unsigned oi = t / 15u, oj = t - oi * 15u;
        const float* xb = x + (size_t)b * 3072 + oi * 64 + oj * 2;
        #pragma unroll
        for (int j = 0; j < 8; ++j) {
            int k = kc * 8 + j;
            float v = 0.f;
            if (k < 27) {
                int c = k / 9, rr = k - c * 9;
                int kh = rr / 3, kw = rr - kh * 3;
                v = xb[c * 1024 + kh * 32 + kw];
            } else if (k == 27) {
                v = 1.0f;
            }
            unsigned short hh, mm, ll;
            tsplit(v, hh, mm, ll);
            ah[s][j] = (short)hh; am[s][j] = (short)mm; al[s][j] = (short)ll;
        }
    }
    __syncthreads();

    const bf16x8s* SBC = (const bf16x8s*)SB;

    f32x4 best[4];
    int   bidx[4][4];
    #pragma unroll
    for (int s = 0; s < 4; ++s) {
        best[s] = (f32x4){-1e30f, -1e30f, -1e30f, -1e30f};
        #pragma unroll
        for (int i = 0; i < 4; ++i) bidx[s][i] = 0;
    }

    #pragma unroll
    for (int ct = 0; ct < 16; ++ct) {
        bf16x8s bh = SBC[ct * 192 + lane];
        bf16x8s bm = SBC[ct * 192 + 64 + lane];
        bf16x8s bl = SBC[ct * 192 + 128 + lane];
        #pragma unroll
        for (int s = 0; s < 4; ++s) {
            f32x4 a = {0.f, 0.f, 0.f, 0.f};
            a = mm6(ah[s], am[s], al[s], bh, bm, bl, a);
            #pragma unroll
            for (int i = 0; i < 4; ++i) {
                bool g = a[i] > best[s][i];
                best[s][i] = g ? a[i] : best[s][i];
                bidx[s][i] = g ? (ct * 16 + col) : bidx[s][i];
            }
        }
    }

    #pragma unroll
    for (int m = 1; m < 16; m <<= 1) {
        #pragma unroll
        for (int s = 0; s < 4; ++s)
            #pragma unroll
            for (int i = 0; i < 4; ++i) {
                float ob = __shfl_xor(best[s][i], m, 64);
                int   oi2 = __shfl_xor(bidx[s][i], m, 64);
                if (ob > best[s][i] || (ob == best[s][i] && oi2 < bidx[s][i])) {
                    best[s][i] = ob; bidx[s][i] = oi2;
                }
            }
    }

    if (col == 0) {
        #pragma unroll
        for (int s = 0; s < 4; ++s)
            #pragma unroll
            for (int i = 0; i < 4; ++i) {
                unsigned gp2 = blockIdx.x * 512u + wv * 64u + s * 16u + kc * 4u + i;
                unsigned b2  = gp2 / 225u;
                unsigned t2  = gp2 - b2 * 225u;
                float vm = (float)(bidx[s][i] >> 4) * 0.0625f;
                float vn = (float)(bidx[s][i] & 15) * 0.0625f;
                featbf[(size_t)b2 * FKP + t2]       = (unsigned short)(__float_as_uint(vm) >> 16);
                featbf[(size_t)b2 * FKP + 225 + t2] = (unsigned short)(__float_as_uint(vn) >> 16);
            }
    }
}

// ---------------------------------------------------------------------------
// Fused MLP v2: 2-chain split + tile interleave (4 MFMA streams) + explicit
// depth-1 prefetch of next-kc W (global) and A (LDS) fragments.
// ---------------------------------------------------------------------------
#define H1S 19968   // shorts: 3 terms * 13 kc * 512
#define H2S 10752   // shorts: 3 terms *  7 kc * 512

template <int NT, int KC, int OKC, int NVALID>
__device__ __forceinline__ void layer_mid2(const short* inS, short* outS,
                                           const short* __restrict__ wf,
                                           int wv, int lane) {
    const bf16x8s* Ain = (const bf16x8s*)inS;
    const bf16x8s* Wb  = (const bf16x8s*)wf;
    const int col = lane & 15, g = lane >> 4;
    const bool v0 = (wv < NT);
    const int t0 = v0 ? wv : 0;                          // clamped load index
    constexpr bool TWO = (NT > 8);
    const bool v1 = TWO && (wv + 8 < NT);
    const int t1 = v1 ? (wv + 8) : (NT - 1);             // clamped load index

    f32x4 a0A = {0.f,0.f,0.f,0.f}, a0B = {0.f,0.f,0.f,0.f};
    f32x4 a1A = {0.f,0.f,0.f,0.f}, a1B = {0.f,0.f,0.f,0.f};

    // current fragments (kc = 0)
    bf16x8s Ah = Ain[(0 * KC) * 64 + lane];
    bf16x8s Am = Ain[(1 * KC) * 64 + lane];
    bf16x8s Al = Ain[(2 * KC) * 64 + lane];
    bf16x8s w0h = Wb[(size_t)(t0 * KC) * 192 + lane];
    bf16x8s w0m = Wb[(size_t)(t0 * KC) * 192 + 64 + lane];
    bf16x8s w0l = Wb[(size_t)(t0 * KC) * 192 + 128 + lane];
    bf16x8s w1h, w1m, w1l;
    if constexpr (TWO) {
        w1h = Wb[(size_t)(t1 * KC) * 192 + lane];
        w1m = Wb[(size_t)(t1 * KC) * 192 + 64 + lane];
        w1l = Wb[(size_t)(t1 * KC) * 192 + 128 + lane];
    }

    #pragma unroll
    for (int kc = 0; kc < KC; ++kc) {
        const int kn = (kc + 1 < KC) ? kc + 1 : kc;      // clamped prefetch
        // issue next-kc loads BEFORE this kc's MFMAs
        bf16x8s nAh = Ain[(0 * KC + kn) * 64 + lane];
        bf16x8s nAm = Ain[(1 * KC + kn) * 64 + lane];
        bf16x8s nAl = Ain[(2 * KC + kn) * 64 + lane];
        bf16x8s n0h = Wb[(size_t)(t0 * KC + kn) * 192 + lane];
        bf16x8s n0m = Wb[(size_t)(t0 * KC + kn) * 192 + 64 + lane];
        bf16x8s n0l = Wb[(size_t)(t0 * KC + kn) * 192 + 128 + lane];
        bf16x8s n1h, n1m, n1l;
        if constexpr (TWO) {
            n1h = Wb[(size_t)(t1 * KC + kn) * 192 + lane];
            n1m = Wb[(size_t)(t1 * KC + kn) * 192 + 64 + lane];
            n1l = Wb[(size_t)(t1 * KC + kn) * 192 + 128 + lane];
        }
        // 4 independent streams (2 tiles x 2 chains), interleaved
        a0A = MFMA(Al, w0h, a0A);  if constexpr (TWO) a1A = MFMA(Al, w1h, a1A);
        a0B = MFMA(Ah, w0l, a0B);  if constexpr (TWO) a1B = MFMA(Ah, w1l, a1B);
        a0A = MFMA(Am, w0m, a0A);  if constexpr (TWO) a1A = MFMA(Am, w1m, a1A);
        a0B = MFMA(Am, w0h, a0B);  if constexpr (TWO) a1B = MFMA(Am, w1h, a1B);
        a0A = MFMA(Ah, w0m, a0A);  if constexpr (TWO) a1A = MFMA(Ah, w1m, a1A);
        a0B = MFMA(Ah, w0h, a0B);  if constexpr (TWO) a1B = MFMA(Ah, w1h, a1B);
        Ah = nAh; Am = nAm; Al = nAl;
        w0h = n0h; w0m = n0m; w0l = n0l;
        if constexpr (TWO) { w1h = n1h; w1m = n1m; w1l = n1l; }
    }

    // stores (ReLU + exact split into fragment-major layout)
    {
        int kk = wv * 16 + col;
        if (v0 && kk < NVALID) {
            int kc2 = kk >> 5, oct = (kk >> 3) & 3, j = kk & 7;
            #pragma unroll
            for (int i = 0; i < 4; ++i) {
                int r = g * 4 + i;
                float vv = fmaxf(a0A[i] + a0B[i], 0.f);
                unsigned short hh, mm, ll;
                tsplit(vv, hh, mm, ll);
                outS[((0 * OKC + kc2) * 64 + oct * 16 + r) * 8 + j] = (short)hh;
                outS[((1 * OKC + kc2) * 64 + oct * 16 + r) * 8 + j] = (short)mm;
                outS[((2 * OKC + kc2) * 64 + oct * 16 + r) * 8 + j] = (short)ll;
            }
        }
    }
    if constexpr (TWO) {
        int kk = (wv + 8) * 16 + col;
        if (v1 && kk < NVALID) {
            int kc2 = kk >> 5, oct = (kk >> 3) & 3, j = kk & 7;
            #pragma unroll
            for (int i = 0; i < 4; ++i) {
                int r = g * 4 + i;
                float vv = fmaxf(a1A[i] + a1B[i], 0.f);
                unsigned short hh, mm, ll;
                tsplit(vv, hh, mm, ll);
                outS[((0 * OKC + kc2) * 64 + oct * 16 + r) * 8 + j] = (short)hh;
                outS[((1 * OKC + kc2) * 64 + oct * 16 + r) * 8 + j] = (short)mm;
                outS[((2 * OKC + kc2) * 64 + oct * 16 + r) * 8 + j] = (short)ll;
            }
        }
    }
}

// pad-init helper: slots [K0, K0+NS), bias 1.0 at K0
template <int OKC, int K0, int NS>
__device__ __forceinline__ void pad_init(short* outS, int tid) {
    for (int p = tid; p < NS * 16 * 3; p += 512) {
        int term = p / (NS * 16);
        int rem  = p % (NS * 16);
        int ks   = K0 + rem / 16;
        int r    = rem % 16;
        unsigned short v = (ks == K0 && term == 0) ? 0x3F80 : 0;
        outS[((term * OKC + (ks >> 5)) * 64 + ((ks >> 3) & 3) * 16 + r) * 8 + (ks & 7)] = (short)v;
    }
}

__global__ __launch_bounds__(512, 2) void fused_mlp(
        const unsigned short* __restrict__ featbf,
        const short* __restrict__ wf1, const short* __restrict__ wf2,
        const short* __restrict__ wf3, const short* __restrict__ wf4,
        float* __restrict__ out) {
    __shared__ short FB[H1S + H2S];    // 61,440 B

    const int tid  = threadIdx.x;
    const int wv   = tid >> 6;
    const int lane = tid & 63;
    const int col  = lane & 15, g = lane >> 4;
    const int blk  = blockIdx.x;

    // ---- L1: A (feat, exact 1-term bf16) in regs; flattened (kc,ti) units
    //      with depth-1 W prefetch. acc chains are 12 MFMAs apart -> no stall.
    const unsigned short* fb = featbf + (size_t)(blk * 16 + col) * FKP;
    bf16x8s af[15];
    #pragma unroll
    for (int kc = 0; kc < 15; ++kc)
        af[kc] = *(const bf16x8s*)(fb + kc * 32 + g * 8);

    f32x4 acc1[4];
    #pragma unroll
    for (int i = 0; i < 4; ++i) acc1[i] = (f32x4){0.f, 0.f, 0.f, 0.f};

    {
        const bf16x8s* Wb = (const bf16x8s*)wf1;
        // unit u = kc*4 + tu; tile t = wv + tu*8 (valid if < 25)
        int tl0 = wv;                              // u=0: tu=0 -> t=wv (<25 always)
        bf16x8s cl = Wb[(size_t)(tl0 * 15) * 192 + 128 + lane];
        bf16x8s cm = Wb[(size_t)(tl0 * 15) * 192 + 64 + lane];
        bf16x8s ch = Wb[(size_t)(tl0 * 15) * 192 + lane];
        #pragma unroll
        for (int u = 0; u < 60; ++u) {
            const int kc = u >> 2, tu = u & 3;
            const int t  = wv + tu * 8;
            // prefetch unit u+1 (clamped)
            const int un = (u + 1 < 60) ? u + 1 : u;
            const int knc = un >> 2;
            int tn = wv + (un & 3) * 8; if (tn > 24) tn = 24;
            bf16x8s nl = Wb[(size_t)(tn * 15 + knc) * 192 + 128 + lane];
            bf16x8s nm = Wb[(size_t)(tn * 15 + knc) * 192 + 64 + lane];
            bf16x8s nh = Wb[(size_t)(tn * 15 + knc) * 192 + lane];
            if (t < 25) {                          // wave-uniform guard
                acc1[tu] = MFMA(af[kc], cl, acc1[tu]);
                acc1[tu] = MFMA(af[kc], cm, acc1[tu]);
                acc1[tu] = MFMA(af[kc], ch, acc1[tu]);
            }
            cl = nl; cm = nm; ch = nh;
        }
    }
    // write h1frag (OKC=13, N=400, relu)
    #pragma unroll
    for (int ti = 0; ti < 4; ++ti) {
        int t = wv + ti * 8;
        if (t < 25) {
            int k = t * 16 + col;
            int kc2 = k >> 5, oct = (k >> 3) & 3, j = k & 7;
            #pragma unroll
            for (int i = 0; i < 4; ++i) {
                int r = g * 4 + i;
                float v = fmaxf(acc1[ti][i], 0.f);
                unsigned short hh, mm, ll;
                tsplit(v, hh, mm, ll);
                FB[((0 * 13 + kc2) * 64 + oct * 16 + r) * 8 + j] = (short)hh;
                FB[((1 * 13 + kc2) * 64 + oct * 16 + r) * 8 + j] = (short)mm;
                FB[((2 * 13 + kc2) * 64 + oct * 16 + r) * 8 + j] = (short)ll;
            }
        }
    }
    pad_init<13, 400, 16>(FB, tid);
    __syncthreads();

    // ---- L2: h1frag -> h2frag ----
    layer_mid2<13, 13, 7, 200>(FB, FB + H1S, wf2, wv, lane);
    pad_init<7, 200, 24>(FB + H1S, tid);
    __syncthreads();

    // ---- L3: h2frag -> h3frag (aliases h1frag region) ----
    layer_mid2<7, 7, 4, 100>(FB + H1S, FB, wf3, wv, lane);
    pad_init<4, 100, 28>(FB, tid);
    __syncthreads();

    // ---- L4: wave 0 only; 2-chain ----
    if (wv == 0) {
        const bf16x8s* Ain = (const bf16x8s*)FB;
        f32x4 aA = {0.f, 0.f, 0.f, 0.f}, aB = {0.f, 0.f, 0.f, 0.f};
        #pragma unroll
        for (int kc = 0; kc < 4; ++kc) {
            bf16x8s Ah = Ain[(0 * 4 + kc) * 64 + lane];
            bf16x8s Am = Ain[(1 * 4 + kc) * 64 + lane];
            bf16x8s Al = Ain[(2 * 4 + kc) * 64 + lane];
            const bf16x8s* W = (const bf16x8s*)(wf4 + (size_t)kc * 1536);
            bf16x8s wh = W[lane], wm = W[64 + lane], wl = W[128 + lane];
            aA = MFMA(Al, wh, aA);  aB = MFMA(Ah, wl, aB);
            aA = MFMA(Am, wm, aA);  aB = MFMA(Am, wh, aB);
            aA = MFMA(Ah, wm, aA);  aB = MFMA(Ah, wh, aB);
        }
        if (col < 10) {
            #pragma unroll
            for (int i = 0; i < 4; ++i)
                out[(size_t)(blk * 16 + g * 4 + i) * 10 + col] = aA[i] + aB[i];
        }
    }
}

// ---------------------------------------------------------------------------
extern "C" void kernel_launch(void* const* d_in, const int* in_sizes, int n_in,
                              void* d_out, int out_size, void* d_ws, size_t ws_size,
                              hipStream_t stream) {
    const float* x   = (const float*)d_in[0];
    const float* som = (const float*)d_in[1];
    const float* W1  = (const float*)d_in[2];
    const float* b1  = (const float*)d_in[3];
    const float* W2  = (const float*)d_in[4];
    const float* b2  = (const float*)d_in[5];
    const float* W3  = (const float*)d_in[6];
    const float* b3  = (const float*)d_in[7];
    const float* W4  = (const float*)d_in[8];
    const float* b4  = (const float*)d_in[9];

    char* ws = (char*)d_ws;
    short*          sbuf   = (short*)ws;                          //    49,152 B
    unsigned short* featbf = (unsigned short*)(ws + 49152);       // 1,966,080 B
    short*          wf1    = (short*)(ws + 2015232);              // 1,152,000 B
    short*          wf2    = (short*)(ws + 3167232);              //   519,168 B
    short*          wf3    = (short*)(ws + 3686400);              //   150,528 B
    short*          wf4    = (short*)(ws + 3836928);              //    12,288 B
    float* outp = (float*)d_out;

    prep_all<<<159, 256, 0, stream>>>(som, W1, b1, W2, b2, W3, b3, W4, b4,
                                      sbuf, wf1, wf2, wf3, wf4, featbf);
    som_mfma<<<900, 512, 0, stream>>>(x, sbuf, featbf);
    fused_mlp<<<128, 512, 0, stream>>>(featbf, wf1, wf2, wf3, wf4, outp);
}